// Round 7
// baseline (363.639 us; speedup 1.0000x reference)
//
#include <hip/hip_runtime.h>
#include <hip/hip_bf16.h>

#define Bb   2
#define Ss   2048
#define Dd   2048
#define Hh   16
#define KVHh 4
#define HDd  128
#define QKVW 3072   // fused Q|K|V row width

typedef __bf16 bf16x8 __attribute__((ext_vector_type(8)));
typedef float f32x4 __attribute__((ext_vector_type(4)));

__device__ __forceinline__ unsigned short f2bf(float f) {
    unsigned u = __float_as_uint(f);
    unsigned r = (u + 0x7FFFu + ((u >> 16) & 1u)) >> 16;   // RNE
    return (unsigned short)r;
}
__device__ __forceinline__ float bfu2f(unsigned short u) {
    return __uint_as_float(((unsigned)u) << 16);
}

// async global->LDS, 16B per lane; lds base must be wave-uniform (HW adds lane*16)
#define GLOAD16(g, l) __builtin_amdgcn_global_load_lds( \
    (const __attribute__((address_space(1))) unsigned int*)(g), \
    (__attribute__((address_space(3))) unsigned int*)(l), 16, 0, 0)

// fp32 -> bf16 elementwise, 4 elems/thread
__global__ __launch_bounds__(256)
void cast_bf16(const float* __restrict__ X, unsigned short* __restrict__ Y)
{
    int idx = blockIdx.x * 256 + threadIdx.x;
    float4 v = reinterpret_cast<const float4*>(X)[idx];
    ushort4 o;
    o.x = f2bf(v.x); o.y = f2bf(v.y); o.z = f2bf(v.z); o.w = f2bf(v.w);
    reinterpret_cast<ushort4*>(Y)[idx] = o;
}

// All four weight transposes in ONE dispatch.
__global__ __launch_bounds__(256)
void wt_cast_all(const float* __restrict__ wq, const float* __restrict__ wk,
                 const float* __restrict__ wv, const float* __restrict__ wo,
                 unsigned short* __restrict__ wqkvT, unsigned short* __restrict__ woT)
{
    __shared__ float tile[32][33];
    int id = blockIdx.x;
    const float* W; unsigned short* WT; int N, kx, ny;
    if (id < 4096)      {            W = wq; WT = wqkvT;                        N = 2048; kx = id & 63; ny = id >> 6; }
    else if (id < 5120) { id -= 4096; W = wk; WT = wqkvT + (size_t)2048 * 2048; N = 512;  kx = id & 63; ny = id >> 6; }
    else if (id < 6144) { id -= 5120; W = wv; WT = wqkvT + (size_t)2560 * 2048; N = 512;  kx = id & 63; ny = id >> 6; }
    else                { id -= 6144; W = wo; WT = woT;                         N = 2048; kx = id & 63; ny = id >> 6; }
    const int K = 2048;
    int k0 = kx * 32, n0 = ny * 32;
    int tx = threadIdx.x & 31, ty = threadIdx.x >> 5;   // 32 x 8
    #pragma unroll
    for (int i = 0; i < 32; i += 8)
        tile[ty + i][tx] = W[(size_t)(k0 + ty + i) * N + n0 + tx];
    __syncthreads();
    #pragma unroll
    for (int i = 0; i < 32; i += 8)
        WT[(size_t)(n0 + ty + i) * K + k0 + tx] = f2bf(tile[tx][ty + i]);
}

// C[M,N] = A[M,K] @ BT[N,K]^T, bf16 in, fp32 acc, fp32/bf16 out.
//
// Round-12: 256x256 tile, 8 waves (2Mx4N, 512 thr), BK=32 with FOUR LDS
// buffers (128KB) -> true 2-K-tile-deep pipeline: while computing tile t we
// stage tile t+2; boundary wait is a constant counted vmcnt(4) (t+1's 4
// loads must be down, t+2's 4 stay IN FLIGHT across the raw barrier) — the
// T3/T4 schedule that the old 2-barrier/vmcnt(0) 128-tile loop structurally
// could not do (8-phase counted-vs-drain0 = +38-73% per guide).
// st_16x32 swizzle (T2): tiles stored [256 rows][32 k] bf16 (64B rows),
// byte ^= ((byte>>9)&1)<<5 => ds_read_b128 16-way -> ~4-way conflicts.
// Both-sides: pre-swizzled GLOBAL source chunk (DMA writes linearly) +
// swizzled read chunk. setprio(1) around each 16-MFMA cluster (T5).
template<bool BF16OUT>
__global__ __launch_bounds__(512, 2)
void gemm256(const unsigned short* __restrict__ A,
             const unsigned short* __restrict__ BT,
             void* __restrict__ Cv, int M, int N, int K)
{
    __shared__ __align__(16) unsigned short sA[4][256 * 32];   // 64KB: 4 bufs x [256][32]
    __shared__ __align__(16) unsigned short sB[4][256 * 32];   // 64KB
    const int tid  = threadIdx.x;
    const int w    = tid >> 6;
    const int lane = tid & 63;
    const int m    = lane & 15;
    const int quad = lane >> 4;
    const int wm   = w >> 2;          // 0..1  (M half)
    const int wn   = w & 3;           // 0..3  (N quarter)
    const int m0   = blockIdx.y * 256, n0 = blockIdx.x * 256;

    // staging: thread t -> LDS byte t*16 of an 8KB half-tile (linear dest);
    // source chunk pre-swizzled so that swizzled reads see logical layout.
    const int srow = tid >> 2;                               // 0..127
    const int scol = (tid & 3) ^ (((tid >> 5) & 1) << 1);    // 8-elem k-chunk
    // read-side swizzled chunk: phys = row*64 + (quad ^ ((row>>3)&1)<<1)*16,
    // and (row>>3)&1 == (m>>3)&1 for all our frag rows.
    const int chk  = quad ^ (((m >> 3) & 1) << 1);

    f32x4 acc[8][4];
    #pragma unroll
    for (int fm = 0; fm < 8; ++fm)
        #pragma unroll
        for (int fn = 0; fn < 4; ++fn) acc[fm][fn] = (f32x4){0.f, 0.f, 0.f, 0.f};

    // stage half h (rows h*128..h*128+127) of K-tile T for both operands
    auto STAGE2 = [&](int T, int h) {
        const int buf = T & 3;
        GLOAD16(A  + (size_t)(m0 + h * 128 + srow) * K + T * 32 + scol * 8,
                (char*)sA + buf * 16384 + h * 8192 + w * 1024);
        GLOAD16(BT + (size_t)(n0 + h * 128 + srow) * K + T * 32 + scol * 8,
                (char*)sB + buf * 16384 + h * 8192 + w * 1024);
    };

    const int NT = K >> 5;   // K-tiles of 32 (>= 2 for our shapes)

    // prologue: tiles 0 and 1 fully staged; wait tile 0 (tile 1 in flight)
    STAGE2(0, 0); STAGE2(0, 1); STAGE2(1, 0); STAGE2(1, 1);
    asm volatile("s_waitcnt vmcnt(4)" ::: "memory");
    __builtin_amdgcn_s_barrier();
    __builtin_amdgcn_sched_barrier(0);

    #pragma unroll 1
    for (int t = 0; t < NT; ++t) {
        const int buf = t & 3;
        const char* ab = (const char*)sA + buf * 16384 + wm * 8192;
        const char* bb = (const char*)sB + buf * 16384 + (wn >> 1) * 8192 + (wn & 1) * 4096;

        // ---- phase 0: B frags (kept for both phases) + A frags 0-3 ----
        bf16x8 bf[4], af[4];
        #pragma unroll
        for (int fn = 0; fn < 4; ++fn)
            bf[fn] = *(const bf16x8*)(bb + (fn * 16 + m) * 64 + chk * 16);
        #pragma unroll
        for (int j = 0; j < 4; ++j)
            af[j] = *(const bf16x8*)(ab + (j * 16 + m) * 64 + chk * 16);
        if (t + 2 < NT) STAGE2(t + 2, 0);
        __builtin_amdgcn_sched_barrier(0);
        __builtin_amdgcn_s_barrier();
        __builtin_amdgcn_sched_barrier(0);
        __builtin_amdgcn_s_setprio(1);
        #pragma unroll
        for (int j = 0; j < 4; ++j)
            #pragma unroll
            for (int fn = 0; fn < 4; ++fn)
                acc[j][fn] = __builtin_amdgcn_mfma_f32_16x16x32_bf16(
                    af[j], bf[fn], acc[j][fn], 0, 0, 0);
        __builtin_amdgcn_s_setprio(0);
        __builtin_amdgcn_s_barrier();
        __builtin_amdgcn_sched_barrier(0);

        // ---- phase 1: A frags 4-7 ----
        #pragma unroll
        for (int j = 0; j < 4; ++j)
            af[j] = *(const bf16x8*)(ab + ((4 + j) * 16 + m) * 64 + chk * 16);
        if (t + 2 < NT) STAGE2(t + 2, 1);
        __builtin_amdgcn_sched_barrier(0);
        __builtin_amdgcn_s_barrier();
        __builtin_amdgcn_sched_barrier(0);
        __builtin_amdgcn_s_setprio(1);
        #pragma unroll
        for (int j = 0; j < 4; ++j)
            #pragma unroll
            for (int fn = 0; fn < 4; ++fn)
                acc[4 + j][fn] = __builtin_amdgcn_mfma_f32_16x16x32_bf16(
                    af[j], bf[fn], acc[4 + j][fn], 0, 0, 0);
        __builtin_amdgcn_s_setprio(0);

        // ---- tile boundary: t+1 must be landed; t+2 stays in flight ----
        if (t + 2 < NT)      asm volatile("s_waitcnt vmcnt(4)" ::: "memory");
        else if (t + 1 < NT) asm volatile("s_waitcnt vmcnt(0)" ::: "memory");
        __builtin_amdgcn_s_barrier();
        __builtin_amdgcn_sched_barrier(0);
    }

    // epilogue: C/D layout row = quad*4+e, col = m (verified mapping)
    #pragma unroll
    for (int fm = 0; fm < 8; ++fm)
        #pragma unroll
        for (int fn = 0; fn < 4; ++fn)
            #pragma unroll
            for (int e = 0; e < 4; ++e) {
                size_t row = m0 + wm * 128 + fm * 16 + quad * 4 + e;
                size_t col = n0 + wn * 64 + fn * 16 + m;
                if (BF16OUT)
                    ((unsigned short*)Cv)[row * N + col] = f2bf(acc[fm][fn][e]);
                else
                    ((float*)Cv)[row * N + col] = acc[fm][fn][e];
            }
}

// RoPE on fused QKV buffer: heads 0..15 = Q (scaled), 16..19 = K.
__global__ __launch_bounds__(256)
void rope_all(unsigned short* __restrict__ qkv, const float* __restrict__ cosT,
              const float* __restrict__ sinT)
{
    const int h   = blockIdx.y;
    const int row = blockIdx.x * 4 + (threadIdx.x >> 6);
    const int i   = threadIdx.x & 63;
    const int s   = row & (Ss - 1);
    const float scale = (h < Hh) ? 0.08838834764831845f : 1.0f;
    unsigned short* xp = qkv + (size_t)row * QKVW + h * HDd;
    float x1 = bfu2f(xp[i]);
    float x2 = bfu2f(xp[i + 64]);
    float c1 = cosT[s * HDd + i];
    float c2 = cosT[s * HDd + i + 64];
    float s1 = sinT[s * HDd + i];
    float s2 = sinT[s * HDd + i + 64];
    xp[i]      = f2bf((x1 * c1 - x2 * s1) * scale);
    xp[i + 64] = f2bf((x2 * c2 + x1 * s2) * scale);
}

// V (cols 2560.. of QKVraw [B*S,3072] bf16) -> VT [B,KVH,128,S] bf16
__global__ __launch_bounds__(256)
void vt_cast_bf(const unsigned short* __restrict__ KV,
                unsigned short* __restrict__ VT)
{
    __shared__ unsigned short tile[32][34];
    int st = blockIdx.x * 32, dt = blockIdx.y * 32;
    int bk = blockIdx.z;
    int b = bk >> 2, kvh = bk & 3;
    int tx = threadIdx.x & 31, ty = threadIdx.x >> 5;   // 32 x 8
    #pragma unroll
    for (int i = 0; i < 32; i += 8)
        tile[ty + i][tx] = KV[(size_t)(b * Ss + st + ty + i) * QKVW + 2560 + kvh * HDd + dt + tx];
    __syncthreads();
    #pragma unroll
    for (int i = 0; i < 32; i += 8)
        VT[(((size_t)b * KVHh + kvh) * HDd + dt + ty + i) * Ss + st + tx] =
            tile[tx][ty + i];
}

// Flash attention (round-11 structure, unchanged: union loop + counted-vmcnt
// triple-buffer pipeline + both-sides swizzles; verified 84.6us).
__global__ __launch_bounds__(256, 2)
void flash_attn(const unsigned short* __restrict__ qkv,  // [B*S,3072] bf16
                const unsigned short* __restrict__ VT,   // [B,KVH,128,S] bf16
                const float* __restrict__ alibi,         // [B,S,S]
                const float* __restrict__ amask,         // [B,S]
                unsigned short* __restrict__ ctx)        // [B*S,2048] bf16
{
    __shared__ __align__(16) unsigned short kbuf[3][32 * 128];
    __shared__ __align__(16) unsigned short vbuf[3][128 * 32];
    __shared__ __align__(16) float          abuf[3][2][512];
    __shared__ __align__(16) float          am_lds[Ss];
    __shared__ unsigned short s_p[4][16][56];

    const int tid  = threadIdx.x;
    const int w    = tid >> 6;
    const int m    = tid & 15;
    const int quad = (tid & 63) >> 4;

    const int kvh = blockIdx.y;
    const int b   = blockIdx.z;
    const int h   = kvh * 4 + w;

    const int x    = blockIdx.x;
    const int qtA0 = (x & 1) ? (63 - (x >> 1)) : (x >> 1);
    const int qtA  = b ? (63 - qtA0) : qtA0;
    const int qtB  = 127 - qtA;
    const int qA0  = qtA * 16, qB0 = qtB * 16;
    const int ntA  = (qA0 + 47) >> 5;
    const int ntB  = (qB0 + 47) >> 5;

    const unsigned short* vt0 = VT + ((size_t)b * KVHh + kvh) * HDd * Ss;
    const float* amrow = amask + (size_t)b * Ss;
    const float* arowA = alibi + ((size_t)b * Ss + qA0) * Ss;
    const float* arowB = alibi + ((size_t)b * Ss + qB0) * Ss;
    const unsigned short* kgbase = qkv + (size_t)b * Ss * QKVW + 2048 + kvh * HDd;

    const int krow_s = tid >> 4;
    const int koff_b = ((tid & 15) * 16) ^ ((krow_s & 7) << 4);
    const int vrow_s = tid >> 2;
    const int vchk_s = (tid & 3) ^ ((vrow_s >> 1) & 3);
    const int dstw   = w * 512;

    {
        const float* ag = amrow + tid * 4;
        GLOAD16(ag,        am_lds + w * 256);
        GLOAD16(ag + 1024, am_lds + 1024 + w * 256);
    }
    bf16x8 qaA[4], qaB[4];
    {
        const unsigned short* qrA = qkv + (size_t)(b * Ss + qA0 + m) * QKVW + h * HDd;
        const unsigned short* qrB = qkv + (size_t)(b * Ss + qB0 + m) * QKVW + h * HDd;
        #pragma unroll
        for (int c = 0; c < 4; ++c) {
            qaA[c] = *reinterpret_cast<const bf16x8*>(qrA + c * 32 + quad * 8);
            qaB[c] = *reinterpret_cast<const bf16x8*>(qrB + c * 32 + quad * 8);
        }
    }

    f32x4 oA[8], oB[8];
    #pragma unroll
    for (int f = 0; f < 8; ++f) {
        oA[f] = (f32x4){0.f, 0.f, 0.f, 0.f};
        oB[f] = (f32x4){0.f, 0.f, 0.f, 0.f};
    }
    float lA[4] = {0.f, 0.f, 0.f, 0.f}, lB[4] = {0.f, 0.f, 0.f, 0.f};

    auto STAGE = [&](int kn, int buf, bool aact) {
        const unsigned short* kg =
            kgbase + (size_t)(kn + krow_s) * QKVW + (koff_b >> 1);
        GLOAD16(kg,              &kbuf[buf][dstw]);
        GLOAD16(kg + 16 * QKVW,  &kbuf[buf][2048 + dstw]);
        const unsigned short* vg = vt0 + (size_t)vrow_s * Ss + kn + vchk_s * 8;
        GLOAD16(vg,             &vbuf[buf][dstw]);
        GLOAD16(vg + 64 * Ss,   &vbuf[buf][2048 + dstw]);
        if (tid < 128) {
            if (aact) {
                const float* ag = arowA + (size_t)(tid >> 3) * Ss + kn + (tid & 7) * 4;
                GLOAD16(ag, &abuf[buf][0][w * 256]);
            }
        } else {
            const float* ag = arowB + (size_t)((tid - 128) >> 3) * Ss + kn + (tid & 7) * 4;
            GLOAD16(ag, &abuf[buf][1][(w - 2) * 256]);
        }
    };

    STAGE(0, 0, true);
    asm volatile("s_waitcnt vmcnt(0)" ::: "memory");
    __syncthreads();

    int cur = 0;
    #pragma unroll 1
    for (int kt = 0; kt < ntB; ++kt) {
        const int k0  = kt * 32;
        const int nxt = (cur == 2) ? 0 : cur + 1;
        const bool aact = kt < ntA;

        if (kt + 1 < ntB) {
            const bool aactn = (kt + 1) < ntA;
            STAGE(k0 + 32, nxt, aactn);
            if (w < 2) {
                if (aactn) asm volatile("s_waitcnt vmcnt(5)" ::: "memory");
                else       asm volatile("s_waitcnt vmcnt(4)" ::: "memory");
            } else       asm volatile("s_waitcnt vmcnt(5)" ::: "memory");
        } else {
            asm volatile("s_waitcnt vmcnt(0)" ::: "memory");
        }
        __builtin_amdgcn_s_barrier();
        __builtin_amdgcn_sched_barrier(0);

        const float am0 = am_lds[k0 + m];
        const float am1 = am_lds[k0 + 16 + m];

        const char* kb  = (const char*)&kbuf[cur][0];
        const char* vbp = (const char*)&vbuf[cur][0];
        const int  ksw  = (m & 7) << 4;
        const int  vsw  = ((m >> 1) & 3) << 4;
        bf16x8 kf0[4], kf1[4];
        #pragma unroll
        for (int c = 0; c < 4; ++c) {
            kf0[c] = *(const bf16x8*)(kb + m * 256        + ((c * 64 + quad * 16) ^ ksw));
            kf1[c] = *(const bf16x8*)(kb + (16 + m) * 256 + ((c * 64 + quad * 16) ^ ksw));
        }
        bf16x8 vf[8];
        #pragma unroll
        for (int f = 0; f < 8; ++f)
            vf[f] = *(const bf16x8*)(vbp + (f * 16 + m) * 64 + ((quad * 16) ^ vsw));

        {
            f32x4 s0 = {0.f, 0.f, 0.f, 0.f}, s1 = {0.f, 0.f, 0.f, 0.f};
            #pragma unroll
            for (int c = 0; c < 4; ++c) {
                s0 = __builtin_amdgcn_mfma_f32_16x16x32_bf16(qaB[c], kf0[c], s0, 0, 0, 0);
                s1 = __builtin_amdgcn_mfma_f32_16x16x32_bf16(qaB[c], kf1[c], s1, 0, 0, 0);
            }
            #pragma unroll
            for (int r = 0; r < 4; ++r) {
                const int row = quad * 4 + r;
                const int qi  = qB0 + row;
                float x0 = s0[r] + abuf[cur][1][row * 32 + m]      + am0;
                float x1 = s1[r] + abuf[cur][1][row * 32 + 16 + m] + am1;
                x0 = (k0 + m      <= qi) ? x0 : -1e30f;
                x1 = (k0 + 16 + m <= qi) ? x1 : -1e30f;
                const float p0 = __expf(x0);
                const float p1 = __expf(x1);
                lB[r] += p0 + p1;
                s_p[w][row][m]      = f2bf(p0);
                s_p[w][row][16 + m] = f2bf(p1);
            }
            __builtin_amdgcn_wave_barrier();
            const bf16x8 pa = *reinterpret_cast<const bf16x8*>(&s_p[w][m][quad * 8]);
            __builtin_amdgcn_wave_barrier();
            #pragma unroll
            for (int f = 0; f < 8; ++f)
                oB[f] = __builtin_amdgcn_mfma_f32_16x16x32_bf16(pa, vf[f], oB[f], 0, 0, 0);
        }

        if (aact) {
            f32x4 s0 = {0.f, 0.f, 0.f, 0.f}, s1 = {0.f, 0.f, 0.f, 0.f};
            #pragma unroll
            for (int c = 0; c < 4; ++c) {
                s0 = __builtin_amdgcn_mfma_f32_16x16x32_bf16(qaA[c], kf0[c], s0, 0, 0, 0);
                s1 = __builtin_amdgcn_mfma_f32_16x16x32_bf16(qaA[c], kf1[c], s1, 0, 0, 0);
            }
            #pragma unroll
            for (int r = 0; r < 4; ++r) {
                const int row = quad * 4 + r;
                const int qi  = qA0 + row;
                float x0 = s0[r] + abuf[cur][0][row * 32 + m]      + am0;
                float x1 = s1[r] + abuf[cur][0][row * 32 + 16 + m] + am1;
                x0 = (k0 + m      <= qi) ? x0 : -1e30f;
                x1 = (k0 + 16 + m <= qi) ? x1 : -1e30f;
                const float p0 = __expf(x0);
                const float p1 = __expf(x1);
                lA[r] += p0 + p1;
                s_p[w][row][m]      = f2bf(p0);
                s_p[w][row][16 + m] = f2bf(p1);
            }
            __builtin_amdgcn_wave_barrier();
            const bf16x8 pa = *reinterpret_cast<const bf16x8*>(&s_p[w][m][quad * 8]);
            __builtin_amdgcn_wave_barrier();
            #pragma unroll
            for (int f = 0; f < 8; ++f)
                oA[f] = __builtin_amdgcn_mfma_f32_16x16x32_bf16(pa, vf[f], oA[f], 0, 0, 0);
        }

        cur = nxt;
    }

    float invA[4], invB[4];
    #pragma unroll
    for (int r = 0; r < 4; ++r) {
        float la = lA[r], lb = lB[r];
        la += __shfl_xor(la, 1, 64); lb += __shfl_xor(lb, 1, 64);
        la += __shfl_xor(la, 2, 64); lb += __shfl_xor(lb, 2, 64);
        la += __shfl_xor(la, 4, 64); lb += __shfl_xor(lb, 4, 64);
        la += __shfl_xor(la, 8, 64); lb += __shfl_xor(lb, 8, 64);
        invA[r] = 1.f / la; invB[r] = 1.f / lb;
    }
    #pragma unroll
    for (int f = 0; f < 8; ++f)
        #pragma unroll
        for (int r = 0; r < 4; ++r) {
            ctx[(size_t)(b * Ss + qA0 + quad * 4 + r) * Dd + h * HDd + f * 16 + m] =
                f2bf(oA[f][r] * invA[r]);
            ctx[(size_t)(b * Ss + qB0 + quad * 4 + r) * Dd + h * HDd + f * 16 + m] =
                f2bf(oB[f][r] * invB[r]);
        }
}

extern "C" void kernel_launch(void* const* d_in, const int* in_sizes, int n_in,
                              void* d_out, int out_size, void* d_ws, size_t ws_size,
                              hipStream_t stream) {
    const float* hidden = (const float*)d_in[0];
    const float* cosT   = (const float*)d_in[1];
    const float* sinT   = (const float*)d_in[2];
    const float* alibi  = (const float*)d_in[3];
    const float* amask  = (const float*)d_in[4];
    const float* wq     = (const float*)d_in[5];
    const float* wk     = (const float*)d_in[6];
    const float* wv     = (const float*)d_in[7];
    const float* wo     = (const float*)d_in[8];
    float* out = (float*)d_out;

    char* ws = (char*)d_ws;
    unsigned short* Abf    = (unsigned short*)(ws);              // 16,777,216
    unsigned short* wqkvT  = (unsigned short*)(ws + 16777216);   // 12,582,912  [3072][2048]
    unsigned short* woT    = (unsigned short*)(ws + 29360128);   //  8,388,608
    unsigned short* QKVraw = (unsigned short*)(ws + 37748736);   // 25,165,824  [4096][3072]
    unsigned short* VT     = (unsigned short*)(ws + 62914560);   //  4,194,304
    unsigned short* Ctx    = (unsigned short*)(ws + 67108864);   // 16,777,216
    // total: 83,886,080 B

    const int M = Bb * Ss;  // 4096

    cast_bf16<<<(M * Dd / 4) / 256, 256, 0, stream>>>(hidden, Abf);
    wt_cast_all<<<10240, 256, 0, stream>>>(wq, wk, wv, wo, wqkvT, woT);

    // fused Q|K|V projection: 256^2 8-wave deep-pipelined GEMM
    gemm256<true><<<dim3(QKVW / 256, M / 256), 512, 0, stream>>>(Abf, wqkvT, QKVraw, M, QKVW, Dd);

    rope_all<<<dim3(M / 4, 20), 256, 0, stream>>>(QKVraw, cosT, sinT);

    vt_cast_bf<<<dim3(Ss / 32, HDd / 32, Bb * KVHh), 256, 0, stream>>>(QKVraw, VT);

    flash_attn<<<dim3(64, KVHh, Bb), 256, 0, stream>>>(QKVraw, VT, alibi, amask, Ctx);

    gemm256<false><<<dim3(Dd / 256, M / 256), 512, 0, stream>>>(Ctx, woT, out, M, Dd, Dd);
}